// Round 1
// 365.421 us; speedup vs baseline: 1.0606x; 1.0606x over previous
//
#include <hip/hip_runtime.h>

#define HH 512
#define WW 512
#define NB 4
#define NC 25              // final channel count: 1 + 12*2
#define HWs (HH * WW)

__device__ __forceinline__ int refl(int p, int n) {
    p = (p < 0) ? -p : p;
    p = (p >= n) ? (2 * n - 2 - p) : p;
    return p;
}

__global__ __launch_bounds__(256) void copy_x_kernel(const float* __restrict__ x,
                                                     float* __restrict__ out) {
    int t = blockIdx.x * 256 + threadIdx.x;   // NB*HWs/4 = 262144 threads
    int b = t >> 16;                          // HWs/4 = 65536 float4 per batch
    int r = t & 65535;
    const float4* src = (const float4*)(x + (size_t)b * HWs);
    float4* dst = (float4*)(out + (size_t)b * NC * HWs);
    dst[r] = src[r];
}

// Dilation-symmetry register reuse: thread owns 3 output rows spaced DIL
// apart (one column). The 5 loaded rows {h-d..h+3d} x 3 col-taps serve all
// 27 row-taps: 15 dword loads per 3 px (5 vals/px vs 9). Lane = consecutive
// col -> every load is a dense 256B wave-load (4 L1 lines); row bases scalar.
// Rows [3d*floor(512/3d), 512) (<=26) handled by a tail path in-kernel.
//
// R1 changes:
//  - __launch_bounds__(256,4): cap VGPR <=128 -> >=4 waves/SIMD (theory:
//    latency-bound from occupancy collapse in the big-NIN instantiations).
//  - explicit 1-deep channel prefetch (v/vn, wk/wkn) so a full channel's 15
//    loads + 18 weight s_loads are in flight during the previous channel's
//    54 FMAs.
//  - bijective chunked XCD swizzle (8 XCDs): row-sharing neighbor blocks
//    (delta = 2*DIL blocks) stay in one XCD's L2 instead of missing to L3.
template <int NIN, int DIL>
__global__ __launch_bounds__(256, 4) void msd_layer(const float* __restrict__ wts,
                                                    const float* __restrict__ bias,
                                                    float* __restrict__ buf,
                                                    int layer) {
    constexpr int M3 = 512 / (3 * DIL);
    constexpr int DM = DIL * M3;          // row-bases per image
    constexpr int SPAN = 3 * DM;          // rows covered by main path
    constexpr int RT = 512 - SPAN;        // tail rows (0..26)
    constexpr int TCH = (RT + 3) / 4;     // tail chunks of 4 rows
    constexpr int IMT = 512 * DM;         // main threads per image
    constexpr int NMAIN = 4 * IMT;

    // ---- bijective chunked XCD swizzle (MI355X: 8 XCDs, round-robin) ----
    int bid = blockIdx.x;
    {
        const int nblk = gridDim.x;
        const int q = nblk >> 3, r = nblk & 7;
        const int xcd = bid & 7, idx = bid >> 3;
        bid = (xcd < r ? xcd * (q + 1) : r * (q + 1) + (xcd - r) * q) + idx;
    }
    const int t = bid * 256 + threadIdx.x;

    const float b0 = bias[2 * layer];
    const float b1 = bias[2 * layer + 1];

    if (t < NMAIN) {
        const int img = t / IMT;                       // uniform per block
        const int u = t - img * IMT;
        const int bi = __builtin_amdgcn_readfirstlane(u >> 9);   // base index
        const int w = u & 511;                         // per-lane column
        const int k = bi / DIL, j = bi - k * DIL;
        const int h = 3 * DIL * k + j;                 // base output row (scalar)

        int rowoff[5];                                 // rows h+(r-1)*d, scalar
#pragma unroll
        for (int r = 0; r < 5; ++r) rowoff[r] = refl(h + (r - 1) * DIL, HH) * WW;
        int cw[3];                                     // per-lane col taps
#pragma unroll
        for (int q = 0; q < 3; ++q) cw[q] = refl(w + (q - 1) * DIL, WW);

        float a0[3] = {b0, b0, b0};
        float a1[3] = {b1, b1, b1};
        const float* base = buf + (size_t)img * NC * HWs;

        // preload channel 0: pixel block + weights
        float v[5][3];
#pragma unroll
        for (int r = 0; r < 5; ++r) {
            const float* rowp = base + rowoff[r];
#pragma unroll
            for (int q = 0; q < 3; ++q) v[r][q] = rowp[cw[q]];
        }
        float wk0[9], wk1[9];
#pragma unroll
        for (int kk = 0; kk < 9; ++kk) {
            wk0[kk] = wts[kk];                          // uniform -> s_load
            wk1[kk] = wts[NIN * 9 + kk];
        }

#pragma unroll
        for (int c = 0; c < NIN; ++c) {
            // ---- prefetch channel c+1 while FMAs of channel c run ----
            float vn[5][3];
            float wn0[9], wn1[9];
            if (c + 1 < NIN) {
                const float* pn = base + (size_t)(c + 1) * HWs;
#pragma unroll
                for (int r = 0; r < 5; ++r) {
                    const float* rowp = pn + rowoff[r];
#pragma unroll
                    for (int q = 0; q < 3; ++q) vn[r][q] = rowp[cw[q]];
                }
#pragma unroll
                for (int kk = 0; kk < 9; ++kk) {
                    wn0[kk] = wts[(c + 1) * 9 + kk];
                    wn1[kk] = wts[(NIN + c + 1) * 9 + kk];
                }
            }

            // ---- 54 FMAs on the resident channel ----
#pragma unroll
            for (int al = 0; al < 3; ++al)
#pragma unroll
                for (int kr = 0; kr < 3; ++kr)
#pragma unroll
                    for (int kw = 0; kw < 3; ++kw) {
                        float vv = v[al + kr][kw];
                        a0[al] = fmaf(vv, wk0[kr * 3 + kw], a0[al]);
                        a1[al] = fmaf(vv, wk1[kr * 3 + kw], a1[al]);
                    }

            // ---- rotate (SSA-renamed away under full unroll) ----
            if (c + 1 < NIN) {
#pragma unroll
                for (int r = 0; r < 5; ++r)
#pragma unroll
                    for (int q = 0; q < 3; ++q) v[r][q] = vn[r][q];
#pragma unroll
                for (int kk = 0; kk < 9; ++kk) {
                    wk0[kk] = wn0[kk];
                    wk1[kk] = wn1[kk];
                }
            }
        }

        float* o0 = buf + (size_t)(img * NC + NIN) * HWs;
        float* o1 = o0 + HWs;
#pragma unroll
        for (int al = 0; al < 3; ++al) {
            size_t off = (size_t)(h + al * DIL) * WW + (size_t)w;
            o0[off] = fmaxf(a0[al], 0.f);
            o1[off] = fmaxf(a1[al], 0.f);
        }
    } else if (RT > 0) {
        const int t2 = t - NMAIN;
        constexpr int PIT = 512 * TCH;
        const int img = t2 / PIT;
        const int u = t2 - img * PIT;
        const int s = __builtin_amdgcn_readfirstlane(u >> 9);
        const int w = u & 511;
        const int r0 = SPAN + 4 * s;

        int cw[3];
#pragma unroll
        for (int q = 0; q < 3; ++q) cw[q] = refl(w + (q - 1) * DIL, WW);
        int ro[3][4];
#pragma unroll
        for (int kr = 0; kr < 3; ++kr)
#pragma unroll
            for (int i = 0; i < 4; ++i)
                ro[kr][i] = refl(r0 + i + (kr - 1) * DIL, HH) * WW;

        float a0[4] = {b0, b0, b0, b0};
        float a1[4] = {b1, b1, b1, b1};
        const float* base = buf + (size_t)img * NC * HWs;

        for (int c = 0; c < NIN; ++c) {
            const float* plane = base + (size_t)c * HWs;
            float wk0[9], wk1[9];
#pragma unroll
            for (int kk = 0; kk < 9; ++kk) {
                wk0[kk] = wts[c * 9 + kk];
                wk1[kk] = wts[(NIN + c) * 9 + kk];
            }
#pragma unroll
            for (int i = 0; i < 4; ++i) {
                if (r0 + i < HH) {
#pragma unroll
                    for (int kr = 0; kr < 3; ++kr) {
                        const float* rowp = plane + ro[kr][i];
#pragma unroll
                        for (int kw = 0; kw < 3; ++kw) {
                            float vv = rowp[cw[kw]];
                            a0[i] = fmaf(vv, wk0[kr * 3 + kw], a0[i]);
                            a1[i] = fmaf(vv, wk1[kr * 3 + kw], a1[i]);
                        }
                    }
                }
            }
        }

        float* o0 = buf + (size_t)(img * NC + NIN) * HWs;
        float* o1 = o0 + HWs;
#pragma unroll
        for (int i = 0; i < 4; ++i) {
            if (r0 + i < HH) {
                size_t off = (size_t)(r0 + i) * WW + (size_t)w;
                o0[off] = fmaxf(a0[i], 0.f);
                o1[off] = fmaxf(a1[i], 0.f);
            }
        }
    }
}

extern "C" void kernel_launch(void* const* d_in, const int* in_sizes, int n_in,
                              void* d_out, int out_size, void* d_ws, size_t ws_size,
                              hipStream_t stream) {
    const float* x = (const float*)d_in[0];
    const float* bias = (const float*)d_in[1];
    float* out = (float*)d_out;

    copy_x_kernel<<<1024, 256, 0, stream>>>(x, out);

// blocks = (main threads + tail threads) / 256 = 8*DM + 8*TCH
#define GBLK(dil) (8 * ((512 / (3 * (dil))) * (dil)) \
                 + 8 * (((512 - 3 * ((512 / (3 * (dil))) * (dil))) + 3) / 4))
#define LAYER(i, nin, dil) \
    msd_layer<nin, dil><<<GBLK(dil), 256, 0, stream>>>((const float*)d_in[2 + i], bias, out, i)

    LAYER(0, 1, 1);
    LAYER(1, 3, 2);
    LAYER(2, 5, 3);
    LAYER(3, 7, 4);
    LAYER(4, 9, 5);
    LAYER(5, 11, 6);
    LAYER(6, 13, 7);
    LAYER(7, 15, 8);
    LAYER(8, 17, 9);
    LAYER(9, 19, 10);
    LAYER(10, 21, 11);
    LAYER(11, 23, 12);
#undef LAYER
#undef GBLK
}